// Round 12
// baseline (163.060 us; speedup 1.0000x reference)
//
#include <hip/hip_runtime.h>

#define SGRID 14
static constexpr float INV_S = 1.0f / 14.0f;

// address-space-qualified pointer types for global_load_lds
typedef const unsigned int __attribute__((address_space(1)))* gas_ptr;
typedef unsigned int __attribute__((address_space(3)))* las_ptr;

__device__ __forceinline__ void gld_lds16(const void* g, void* l) {
    __builtin_amdgcn_global_load_lds((gas_ptr)g, (las_ptr)l, 16, 0, 0);
}

__device__ __forceinline__ float cell_loss(const float* p, const float* t) {
    float tconf = t[4];
    float obj   = (tconf == 1.0f) ? 1.0f : 0.0f;
    float noobj = (tconf == 0.0f) ? 1.0f : 0.0f;

    float d4 = p[4] - t[4];
    float d9 = p[9] - t[9];
    float no_object_loss = noobj * (d4 * d4 + d9 * d9);

    float class_loss = 0.0f;
    #pragma unroll
    for (int c = 10; c < 30; ++c) { float d = p[c] - t[c]; class_loss += d * d; }
    class_loss *= obj;

    float iou[2];
    #pragma unroll
    for (int b = 0; b < 2; ++b) {
        int o = b * 5;
        float pcx = p[o] * INV_S, pcy = p[o+1] * INV_S, pw = p[o+2], ph = p[o+3];
        float tcx = t[o] * INV_S, tcy = t[o+1] * INV_S, tw = t[o+2], th = t[o+3];
        float px0 = pcx - 0.5f * pw, py0 = pcy - 0.5f * ph;
        float px1 = pcx + 0.5f * pw, py1 = pcy + 0.5f * ph;
        float tx0 = tcx - 0.5f * tw, ty0 = tcy - 0.5f * th;
        float tx1 = tcx + 0.5f * tw, ty1 = tcy + 0.5f * th;
        float lx = fmaxf(px0, tx0), ly = fmaxf(py0, ty0);
        float rx = fminf(px1, tx1), ry = fminf(py1, ty1);
        float wx = fmaxf(rx - lx, 0.0f), wy = fmaxf(ry - ly, 0.0f);
        float inter = wx * wy;
        float ap = (px1 - px0) * (py1 - py0);
        float at = (tx1 - tx0) * (ty1 - ty0);
        float denom = ap + at - inter;
        iou[b] = (denom > 0.0f) ? (inter / denom) : 0.0f;
    }

    bool pick1 = (iou[0] <= iou[1]);
    float chosen = pick1 ? iou[1] : iou[0];
    int o = pick1 ? 5 : 0;

    float dx = p[o]   - t[o];
    float dy = p[o+1] - t[o+1];
    float dw = sqrtf(p[o+2]) - sqrtf(t[o+2]);
    float dh = sqrtf(p[o+3]) - sqrtf(t[o+3]);
    float reg = dx * dx + dy * dy + dw * dw + dh * dh;

    float dconf = p[o+4] - chosen;
    float contain = dconf * dconf;

    return obj * (5.0f * reg + contain) + 0.5f * no_object_loss + class_loss;
}

// R4 champion, verbatim: 4-wave blocks, chunk = 256 cells, single 61.44 KB
// buffer, 2 blocks/CU, sync-drain staging via global_load_lds dwordx4.
__global__ __launch_bounds__(256) void yolo_loss_kernel(
    const float* __restrict__ pred, const float* __restrict__ tgt,
    float* __restrict__ out, int ncells, int nchunks, float invN)
{
    __shared__ float4 sbuf[3840];
    __shared__ float wpart[4];
    const int tid  = threadIdx.x;
    const int lane = tid & 63;
    const int wv   = tid >> 6;
    float sum = 0.0f;

    for (int chunk = blockIdx.x; chunk < nchunks; chunk += gridDim.x) {
        const float4* p4 = (const float4*)(pred + (size_t)chunk * 7680);
        const float4* t4 = (const float4*)(tgt  + (size_t)chunk * 7680);
        const int j0 = wv * 15;
        #pragma unroll
        for (int j = 0; j < 15; ++j) {
            int jj = j0 + j;
            const float4* src = (jj < 30) ? (p4 + jj * 64) : (t4 + (jj - 30) * 64);
            gld_lds16((const void*)(src + lane), (void*)&sbuf[jj * 64]);
        }
        __syncthreads();

        {
            const float* base = (const float*)sbuf;
            const float2* cp2 = (const float2*)(base + tid * 30);
            const float2* ct2 = (const float2*)(base + 7680 + tid * 30);
            float p[30], t[30];
            #pragma unroll
            for (int j = 0; j < 15; ++j) { float2 v = cp2[j]; p[2*j] = v.x; p[2*j+1] = v.y; }
            #pragma unroll
            for (int j = 0; j < 15; ++j) { float2 v = ct2[j]; t[2*j] = v.x; t[2*j+1] = v.y; }
            sum += cell_loss(p, t);
        }
        __syncthreads();
    }

    int rem = ncells - nchunks * 256;
    if (rem > 0 && blockIdx.x == 0 && tid < rem) {
        int cell = nchunks * 256 + tid;
        const float2* p2 = (const float2*)(pred + (size_t)cell * 30);
        const float2* t2 = (const float2*)(tgt  + (size_t)cell * 30);
        float p[30], t[30];
        #pragma unroll
        for (int j = 0; j < 15; ++j) { float2 v = p2[j]; p[2*j] = v.x; p[2*j+1] = v.y; }
        #pragma unroll
        for (int j = 0; j < 15; ++j) { float2 v = t2[j]; t[2*j] = v.x; t[2*j+1] = v.y; }
        sum += cell_loss(p, t);
    }

    #pragma unroll
    for (int off = 32; off > 0; off >>= 1) sum += __shfl_down(sum, off, 64);
    if (lane == 0) wpart[wv] = sum;
    __syncthreads();
    if (tid == 0)
        atomicAdd(out, (wpart[0] + wpart[1] + wpart[2] + wpart[3]) * invN);
}

// DIAGNOSTIC PROBE: pure-read ceiling for this exact footprint. Grid-stride
// float4 over both tensors, 4 independent accumulators (MLP), result folded
// into d_ws (never read by the harness; d_out untouched). rocprof reports
// this dispatch's dur/BW separately -> measured platform ceiling.
__global__ __launch_bounds__(256) void bw_probe_kernel(
    const float4* __restrict__ pred, const float4* __restrict__ tgt,
    float* __restrict__ scratch, int nf4)
{
    int i0 = blockIdx.x * blockDim.x + threadIdx.x;
    const int stride = gridDim.x * blockDim.x;
    float a0 = 0.f, a1 = 0.f, a2 = 0.f, a3 = 0.f;
    for (int i = i0; i < nf4; i += 4 * stride) {
        int i1 = i + stride, i2 = i + 2 * stride, i3 = i + 3 * stride;
        float4 v0 = pred[i];
        float4 w0 = tgt[i];
        a0 += v0.x + v0.y + v0.z + v0.w + w0.x + w0.y + w0.z + w0.w;
        if (i1 < nf4) { float4 v = pred[i1], w = tgt[i1];
            a1 += v.x + v.y + v.z + v.w + w.x + w.y + w.z + w.w; }
        if (i2 < nf4) { float4 v = pred[i2], w = tgt[i2];
            a2 += v.x + v.y + v.z + v.w + w.x + w.y + w.z + w.w; }
        if (i3 < nf4) { float4 v = pred[i3], w = tgt[i3];
            a3 += v.x + v.y + v.z + v.w + w.x + w.y + w.z + w.w; }
    }
    float s = a0 + a1 + a2 + a3;
    #pragma unroll
    for (int off = 32; off > 0; off >>= 1) s += __shfl_down(s, off, 64);
    if ((threadIdx.x & 63) == 0) atomicAdd(scratch, s);
}

extern "C" void kernel_launch(void* const* d_in, const int* in_sizes, int n_in,
                              void* d_out, int out_size, void* d_ws, size_t ws_size,
                              hipStream_t stream) {
    const float* pred = (const float*)d_in[0];
    const float* tgt  = (const float*)d_in[1];
    float* out = (float*)d_out;

    int ncells  = in_sizes[0] / 30;
    int N       = ncells / (SGRID * SGRID);
    float invN  = 1.0f / (float)N;
    int nchunks = ncells / 256;

    hipMemsetAsync(out, 0, sizeof(float) * (out_size > 0 ? out_size : 1), stream);

    int blocks = nchunks < 1 ? 1 : (nchunks < 512 ? nchunks : 512);
    yolo_loss_kernel<<<blocks, 256, 0, stream>>>(pred, tgt, out, ncells, nchunks, invN);

    // ---- diagnostic probe (separate dispatch; d_ws only) ----
    int nf4 = in_sizes[0] / 4;        // 12,057,600 float4 per tensor
    bw_probe_kernel<<<2048, 256, 0, stream>>>(
        (const float4*)pred, (const float4*)tgt, (float*)d_ws, nf4);
}